// Round 9
// baseline (259.196 us; speedup 1.0000x reference)
//
#include <hip/hip_runtime.h>

#define T_TERMS 768
#define NV 6
#define D1 5
#define D2 9
#define T2 (T_TERMS * T_TERMS)                 // 589824
#define PTOT (T2 + T_TERMS + 1)                // 590593
#define NROWS ((unsigned int)PTOT * NV)        // 3,543,558 rows per tensor
#define NOUT (NROWS * (unsigned int)D2)        // 31,892,022 f32 per tensor (== 2 mod 4)
#define ROWS_PER_TILE 256u
#define TILE_DW (ROWS_PER_TILE * D2)           // 2304 dwords per tile
#define NTILES ((NROWS + ROWS_PER_TILE - 1u) / ROWS_PER_TILE)   // 13843
#define TOTAL_TILES (NTILES * 2u)              // 27686 (both tensors)
#define NBLOCKS 2048u                          // 8 persistent blocks x 256 CUs
#define CHUNK_Q (TOTAL_TILES / NBLOCKS)        // 13
#define CHUNK_R (TOTAL_TILES % NBLOCKS)        // 1062

typedef float f4 __attribute__((ext_vector_type(4)));
typedef float f4u __attribute__((ext_vector_type(4), aligned(4)));
typedef float f2 __attribute__((ext_vector_type(2)));

// Kernel 1: l (sum of per-term interval lows of under) + u (sum of highs of
// over) + relu relaxation coefs. One block, 768 threads.
__global__ void bounds_coef_kernel(const float* __restrict__ Pu,
                                   const float* __restrict__ Po,
                                   float* __restrict__ ws) {
    int t = threadIdx.x;
    float tlo = 0.f, thi = 0.f;
    if (t < T_TERMS) {
        f2 r[15];
        const f2* p2 = (const f2*)(Pu + t * (NV * D1));
        #pragma unroll
        for (int i = 0; i < 15; ++i) r[i] = p2[i];
        const float* rf = (const float*)r;
        float clo = 1.f, chi = 1.f;
        #pragma unroll
        for (int v = 0; v < NV; ++v) {
            float lo = rf[v * 5 + 0], hi = lo;
            #pragma unroll
            for (int i = 1; i < 5; ++i) {
                float x = rf[v * 5 + i];
                lo = fminf(lo, x); hi = fmaxf(hi, x);
            }
            float a = clo * lo, b = clo * hi, c = chi * lo, d = chi * hi;
            clo = fminf(fminf(a, b), fminf(c, d));
            chi = fmaxf(fmaxf(a, b), fmaxf(c, d));
        }
        tlo = clo;
        const f2* q2 = (const f2*)(Po + t * (NV * D1));
        #pragma unroll
        for (int i = 0; i < 15; ++i) r[i] = q2[i];
        clo = 1.f; chi = 1.f;
        #pragma unroll
        for (int v = 0; v < NV; ++v) {
            float lo = rf[v * 5 + 0], hi = lo;
            #pragma unroll
            for (int i = 1; i < 5; ++i) {
                float x = rf[v * 5 + i];
                lo = fminf(lo, x); hi = fmaxf(hi, x);
            }
            float a = clo * lo, b = clo * hi, c = chi * lo, d = chi * hi;
            clo = fminf(fminf(a, b), fminf(c, d));
            chi = fmaxf(fmaxf(a, b), fmaxf(c, d));
        }
        thi = chi;
    }
    __shared__ float slo[12], shi[12];
    for (int off = 32; off; off >>= 1) {
        tlo += __shfl_down(tlo, off);
        thi += __shfl_down(thi, off);
    }
    int wave = threadIdx.x >> 6;
    if ((threadIdx.x & 63) == 0) { slo[wave] = tlo; shi[wave] = thi; }
    __syncthreads();
    if (threadIdx.x == 0) {
        float l = 0.f, u = 0.f;
        #pragma unroll
        for (int w = 0; w < 12; ++w) { l += slo[w]; u += shi[w]; }
        float den = (u - l > 0.f) ? (u - l) : 1.f;
        float au, bu, cu, ao, bo, co;
        if (l >= 0.f) {
            au = 0.f; bu = 1.f; cu = 0.f;
            ao = 0.f; bo = 1.f; co = 0.f;
        } else if (u <= 0.f) {
            au = bu = cu = 0.f;
            ao = bo = co = 0.f;
        } else {
            au = 1.f / den; bu = -l / den; cu = 0.f;
            float d2 = den * den;
            ao = u / d2; bo = -2.f * u * l / d2; co = u * l * l / d2;
        }
        ws[0] = au; ws[1] = bu; ws[2] = cu;
        ws[3] = ao; ws[4] = bo; ws[5] = co;
    }
}

// Kernel 2: PERSISTENT expand. 2048 blocks x 256 threads; each block loops
// over a contiguous chunk of (tensor, tile) pairs. Global stores only ever
// wait on LDS data (lgkmcnt) -- never vmcnt -- so the store queue stays full
// across tiles, mimicking the 6.6 TB/s fill kernel's behavior.
__global__ __launch_bounds__(256) void expand_kernel(
        const float* __restrict__ Pu,
        const float* __restrict__ Po,
        const float* __restrict__ coef,
        float* __restrict__ out) {
    __shared__ float lds[TILE_DW];   // 9216 B -> 8 blocks/CU
    static constexpr float Wt[5][5] = {
        {1.0f,        4.0f/8.0f,   6.0f/28.0f,  4.0f/56.0f,  1.0f/70.0f},
        {4.0f/8.0f,   16.0f/28.0f, 24.0f/56.0f, 16.0f/70.0f, 4.0f/56.0f},
        {6.0f/28.0f,  24.0f/56.0f, 36.0f/70.0f, 24.0f/56.0f, 6.0f/28.0f},
        {4.0f/56.0f,  16.0f/70.0f, 24.0f/56.0f, 16.0f/28.0f, 4.0f/8.0f},
        {1.0f/70.0f,  4.0f/56.0f,  6.0f/28.0f,  4.0f/8.0f,   1.0f}
    };

    const unsigned tid = threadIdx.x;
    const unsigned b = blockIdx.x;
    const unsigned gstart = b * CHUNK_Q + (b < CHUNK_R ? b : CHUNK_R);
    const unsigned gcnt = CHUNK_Q + (b < CHUNK_R ? 1u : 0u);

    for (unsigned gi = 0; gi < gcnt; ++gi) {
        const unsigned g = gstart + gi;
        const unsigned ten = (g >= NTILES) ? 1u : 0u;
        const unsigned tile = ten ? g - NTILES : g;
        const float* __restrict__ P = ten ? Po : Pu;
        const float* __restrict__ c3 = coef + ten * 3u;

        const unsigned rr = tile * ROWS_PER_TILE + tid;
        const unsigned nvalid = min(ROWS_PER_TILE, NROWS - tile * ROWS_PER_TILE);

        float c[9] = {0.f,0.f,0.f,0.f,0.f,0.f,0.f,0.f,0.f};
        if (rr < NROWS) {
            unsigned p = rr / 6u;
            unsigned v = rr - p * 6u;
            f4 a4; float a1;
            f4 b4; float b1;
            float scale = 1.f;
            if (p < (unsigned)T2) {
                unsigned t = p / (unsigned)T_TERMS;
                unsigned s = p - t * (unsigned)T_TERMS;
                const float* A = P + (t * NV + v) * D1;
                const float* B = P + (s * NV + v) * D1;
                a4 = *(const f4u*)A;  a1 = A[4];
                b4 = *(const f4u*)B;  b1 = B[4];
                if (v == 0u) scale = c3[0];
            } else if (p < (unsigned)(T2 + T_TERMS)) {
                unsigned t = p - (unsigned)T2;
                const float* A = P + (t * NV + v) * D1;
                a4 = *(const f4u*)A;  a1 = A[4];
                b4 = (f4){1.f,1.f,1.f,1.f};  b1 = 1.f;
                if (v == 0u) scale = c3[1];
            } else {
                a4 = (f4){1.f,1.f,1.f,1.f};  a1 = 1.f;
                b4 = (f4){1.f,1.f,1.f,1.f};  b1 = 1.f;
                if (v == 0u) scale = c3[2];
            }
            float a[5] = {a4.x * scale, a4.y * scale, a4.z * scale, a4.w * scale, a1 * scale};
            float bb[5] = {b4.x, b4.y, b4.z, b4.w, b1};
            #pragma unroll
            for (int i = 0; i < 5; ++i)
                #pragma unroll
                for (int j = 0; j < 5; ++j)
                    c[i + j] = fmaf(Wt[i][j] * a[i], bb[j], c[i + j]);
        }

        // barrier: all threads' ds_reads of the PREVIOUS tile completed before
        // their global stores issued (data dependency), and stores don't touch
        // LDS -- safe to overwrite now.
        __syncthreads();
        #pragma unroll
        for (int k = 0; k < 9; ++k) lds[tid * 9u + k] = c[k];   // stride 9: 2-way, free
        __syncthreads();

        float* __restrict__ ob = out + (size_t)ten * NOUT + (size_t)tile * TILE_DW;
        if (nvalid == ROWS_PER_TILE) {
            if (ten == 0u) {
                const f4* l4 = (const f4*)lds;
                f4* o4 = (f4*)ob;
                o4[tid]         = l4[tid];
                o4[tid + 256u]  = l4[tid + 256u];
                if (tid < 64u) o4[tid + 512u] = l4[tid + 512u];
            } else {
                // base ≡ 2 (mod 4) dwords: peel 2 head + 2 tail, 575 aligned quads
                if (tid < 2u) ob[tid] = lds[tid];
                if (tid >= 2u && tid < 4u) ob[2300u + tid] = lds[2300u + tid];
                const f2* l2 = (const f2*)lds;
                {
                    unsigned q = tid;
                    f2 x = l2[1u + 2u * q], y = l2[2u + 2u * q];
                    f4 vv; vv.x = x.x; vv.y = x.y; vv.z = y.x; vv.w = y.y;
                    *(f4*)(ob + 2u + 4u * q) = vv;
                }
                {
                    unsigned q = tid + 256u;
                    f2 x = l2[1u + 2u * q], y = l2[2u + 2u * q];
                    f4 vv; vv.x = x.x; vv.y = x.y; vv.z = y.x; vv.w = y.y;
                    *(f4*)(ob + 2u + 4u * q) = vv;
                }
                if (tid < 63u) {
                    unsigned q = tid + 512u;
                    f2 x = l2[1u + 2u * q], y = l2[2u + 2u * q];
                    f4 vv; vv.x = x.x; vv.y = x.y; vv.z = y.x; vv.w = y.y;
                    *(f4*)(ob + 2u + 4u * q) = vv;
                }
            }
        } else {
            const unsigned nd = nvalid * 9u;
            for (unsigned x = tid; x < nd; x += 256u) ob[x] = lds[x];
        }
    }
}

extern "C" void kernel_launch(void* const* d_in, const int* in_sizes, int n_in,
                              void* d_out, int out_size, void* d_ws, size_t ws_size,
                              hipStream_t stream) {
    const float* Pu = (const float*)d_in[0];
    const float* Po = (const float*)d_in[1];
    float* ws = (float*)d_ws;
    float* out = (float*)d_out;

    bounds_coef_kernel<<<1, 768, 0, stream>>>(Pu, Po, ws);

    expand_kernel<<<NBLOCKS, 256, 0, stream>>>(Pu, Po, ws, out);
}